// Round 1
// baseline (4638.118 us; speedup 1.0000x reference)
//
#include <hip/hip_runtime.h>
#include <math.h>

#define BB 4
#define SS 2048
#define HH 1024
#define NHEADS 16
#define HD 64
#define DFF_ 4096

// ---------------- LayerNorm: one block per row (H=1024, 256 thr x float4) ----
__device__ __forceinline__ float block_reduce_sum(float v, float* red) {
  const int lane = threadIdx.x & 63;
  const int wid = threadIdx.x >> 6;
#pragma unroll
  for (int off = 32; off > 0; off >>= 1) v += __shfl_down(v, off, 64);
  if (lane == 0) red[wid] = v;
  __syncthreads();
  float s = red[0] + red[1] + red[2] + red[3];
  __syncthreads();
  return s;
}

__global__ __launch_bounds__(256) void ln_kernel(const float* __restrict__ x,
                                                 const float* __restrict__ w,
                                                 const float* __restrict__ bv,
                                                 float* __restrict__ out) {
  __shared__ float red[4];
  const size_t row = blockIdx.x;
  const float* xr = x + row * HH;
  float4 xv = *(const float4*)(xr + threadIdx.x * 4);
  float s = xv.x + xv.y + xv.z + xv.w;
  s = block_reduce_sum(s, red);
  const float mu = s * (1.0f / HH);
  float4 d;
  d.x = xv.x - mu; d.y = xv.y - mu; d.z = xv.z - mu; d.w = xv.w - mu;
  float sq = d.x * d.x + d.y * d.y + d.z * d.z + d.w * d.w;
  sq = block_reduce_sum(sq, red);
  const float rs = rsqrtf(sq * (1.0f / HH) + 1e-12f);
  float4 wv = *(const float4*)(w + threadIdx.x * 4);
  float4 bb = *(const float4*)(bv + threadIdx.x * 4);
  float4 o;
  o.x = d.x * rs * wv.x + bb.x;
  o.y = d.y * rs * wv.y + bb.y;
  o.z = d.z * rs * wv.z + bb.z;
  o.w = d.w * rs * wv.w + bb.w;
  *(float4*)(out + row * HH + threadIdx.x * 4) = o;
}

// ---------------- GEMM: C[M,N] = A[M,K]@W[K,N] + bias (+gelu | +residual) ----
// EPI: 0 = bias only, 1 = bias+exact GELU, 2 = bias+residual
template <int EPI>
__global__ __launch_bounds__(256) void gemm_kernel(const float* __restrict__ A,
                                                   const float* __restrict__ W,
                                                   const float* __restrict__ bias,
                                                   const float* __restrict__ R,
                                                   float* __restrict__ C,
                                                   int M, int N, int K) {
  __shared__ float As[32][68];  // transposed: As[k][m]
  __shared__ float Ws[32][68];  // Ws[k][n]
  const int tid = threadIdx.x;
  const int tx = tid & 15, ty = tid >> 4;
  const int gm0 = blockIdx.y * 64, gn0 = blockIdx.x * 64;
  const int arow = tid >> 2, ac0 = (tid & 3) * 8;
  const int wrow = tid >> 3, wc0 = (tid & 7) * 8;
  const float* Aptr = A + (size_t)(gm0 + arow) * K + ac0;
  const float* Wptr = W + (size_t)wrow * N + gn0 + wc0;
  float acc[4][4] = {};
  for (int kt = 0; kt < K; kt += 32) {
    float4 a0 = *(const float4*)Aptr;
    float4 a1 = *(const float4*)(Aptr + 4);
    float4 w0 = *(const float4*)Wptr;
    float4 w1 = *(const float4*)(Wptr + 4);
    __syncthreads();
    As[ac0 + 0][arow] = a0.x; As[ac0 + 1][arow] = a0.y;
    As[ac0 + 2][arow] = a0.z; As[ac0 + 3][arow] = a0.w;
    As[ac0 + 4][arow] = a1.x; As[ac0 + 5][arow] = a1.y;
    As[ac0 + 6][arow] = a1.z; As[ac0 + 7][arow] = a1.w;
    *(float4*)&Ws[wrow][wc0] = w0;
    *(float4*)&Ws[wrow][wc0 + 4] = w1;
    __syncthreads();
#pragma unroll
    for (int kk = 0; kk < 32; ++kk) {
      float4 av = *(const float4*)&As[kk][ty * 4];
      float4 wv = *(const float4*)&Ws[kk][tx * 4];
      acc[0][0] += av.x * wv.x; acc[0][1] += av.x * wv.y;
      acc[0][2] += av.x * wv.z; acc[0][3] += av.x * wv.w;
      acc[1][0] += av.y * wv.x; acc[1][1] += av.y * wv.y;
      acc[1][2] += av.y * wv.z; acc[1][3] += av.y * wv.w;
      acc[2][0] += av.z * wv.x; acc[2][1] += av.z * wv.y;
      acc[2][2] += av.z * wv.z; acc[2][3] += av.z * wv.w;
      acc[3][0] += av.w * wv.x; acc[3][1] += av.w * wv.y;
      acc[3][2] += av.w * wv.z; acc[3][3] += av.w * wv.w;
    }
    Aptr += 32;
    Wptr += (size_t)32 * N;
  }
  float bn[4];
#pragma unroll
  for (int j = 0; j < 4; ++j) bn[j] = bias[gn0 + tx * 4 + j];
#pragma unroll
  for (int i = 0; i < 4; ++i) {
    const int row = gm0 + ty * 4 + i;
    float v[4];
#pragma unroll
    for (int j = 0; j < 4; ++j) {
      float xv = acc[i][j] + bn[j];
      if (EPI == 1) xv = 0.5f * xv * (1.0f + erff(xv * 0.70710678118654752440f));
      if (EPI == 2) xv += R[(size_t)row * N + gn0 + tx * 4 + j];
      v[j] = xv;
    }
    float4 o = make_float4(v[0], v[1], v[2], v[3]);
    *(float4*)(C + (size_t)row * N + gn0 + tx * 4) = o;
  }
}

// ---------------- Flash attention: 32 q-rows/block, 64-wide k-tiles ----------
__global__ __launch_bounds__(256) void attn_kernel(const float* __restrict__ qkv,
                                                   const float* __restrict__ mask,
                                                   float* __restrict__ ctxout) {
  __shared__ float Qs[32][68];
  __shared__ float Kts[64][68];  // transposed: [d][k]
  __shared__ float Vs[64][68];   // [k][d]
  __shared__ float Ss[32][68];
  __shared__ float Ms[64];
  const int tid = threadIdx.x;
  const int q0 = blockIdx.x * 32;
  const int n = blockIdx.y;
  const int b = blockIdx.z;
  const int r = tid >> 3, g = tid & 7, g8 = g * 8;

  {
    const int row = tid >> 3, c0 = (tid & 7) * 8;
    const float* qp = qkv + ((size_t)(b * SS + q0 + row) * 3) * HH + n * HD + c0;
    float4 v0 = *(const float4*)qp;
    float4 v1 = *(const float4*)(qp + 4);
    *(float4*)&Qs[row][c0] = v0;
    *(float4*)&Qs[row][c0 + 4] = v1;
  }
  __syncthreads();
  float q[64];
#pragma unroll
  for (int t4 = 0; t4 < 16; ++t4) {
    float4 qv = *(const float4*)&Qs[r][t4 * 4];
    q[t4 * 4 + 0] = qv.x; q[t4 * 4 + 1] = qv.y;
    q[t4 * 4 + 2] = qv.z; q[t4 * 4 + 3] = qv.w;
  }

  float m = -1e30f, l = 0.0f;
  float ctxr[8] = {};
  const int krow = tid >> 2, kc0 = (tid & 3) * 16;

  for (int kt = 0; kt < SS; kt += 64) {
    __syncthreads();
    const float* kp = qkv + ((size_t)(b * SS + kt + krow) * 3) * HH + HH + n * HD + kc0;
    const float* vp = kp + HH;
#pragma unroll
    for (int j4 = 0; j4 < 4; ++j4) {
      float4 kv = *(const float4*)(kp + j4 * 4);
      Kts[kc0 + j4 * 4 + 0][krow] = kv.x;
      Kts[kc0 + j4 * 4 + 1][krow] = kv.y;
      Kts[kc0 + j4 * 4 + 2][krow] = kv.z;
      Kts[kc0 + j4 * 4 + 3][krow] = kv.w;
      float4 vv = *(const float4*)(vp + j4 * 4);
      *(float4*)&Vs[krow][kc0 + j4 * 4] = vv;
    }
    if (tid < 64) Ms[tid] = mask[(size_t)b * SS + kt + tid];
    __syncthreads();

    float sv[8];
#pragma unroll
    for (int j = 0; j < 8; ++j) sv[j] = 0.0f;
#pragma unroll
    for (int t = 0; t < 64; ++t) {
      const float qt = q[t];
      float4 ka = *(const float4*)&Kts[t][g8];
      float4 kb = *(const float4*)&Kts[t][g8 + 4];
      sv[0] += qt * ka.x; sv[1] += qt * ka.y; sv[2] += qt * ka.z; sv[3] += qt * ka.w;
      sv[4] += qt * kb.x; sv[5] += qt * kb.y; sv[6] += qt * kb.z; sv[7] += qt * kb.w;
    }
    float tmax = -1e30f;
#pragma unroll
    for (int j = 0; j < 8; ++j) {
      sv[j] = sv[j] * 0.125f + Ms[g8 + j];
      tmax = fmaxf(tmax, sv[j]);
    }
    tmax = fmaxf(tmax, __shfl_xor(tmax, 1, 64));
    tmax = fmaxf(tmax, __shfl_xor(tmax, 2, 64));
    tmax = fmaxf(tmax, __shfl_xor(tmax, 4, 64));
    const float mnew = fmaxf(m, tmax);
    const float scale = expf(m - mnew);
    float psum = 0.0f;
#pragma unroll
    for (int j = 0; j < 8; ++j) {
      const float p = expf(sv[j] - mnew);
      Ss[r][g8 + j] = p;
      psum += p;
    }
    psum += __shfl_xor(psum, 1, 64);
    psum += __shfl_xor(psum, 2, 64);
    psum += __shfl_xor(psum, 4, 64);
    l = l * scale + psum;
    m = mnew;
#pragma unroll
    for (int i = 0; i < 8; ++i) ctxr[i] *= scale;
    __syncthreads();
#pragma unroll 8
    for (int k = 0; k < 64; ++k) {
      const float p = Ss[r][k];
      float4 va = *(const float4*)&Vs[k][g8];
      float4 vb = *(const float4*)&Vs[k][g8 + 4];
      ctxr[0] += p * va.x; ctxr[1] += p * va.y; ctxr[2] += p * va.z; ctxr[3] += p * va.w;
      ctxr[4] += p * vb.x; ctxr[5] += p * vb.y; ctxr[6] += p * vb.z; ctxr[7] += p * vb.w;
    }
  }
  const float inv = 1.0f / l;
  float* op = ctxout + (size_t)(b * SS + q0 + r) * HH + n * HD + g8;
  float4 oa, ob;
  oa.x = ctxr[0] * inv; oa.y = ctxr[1] * inv; oa.z = ctxr[2] * inv; oa.w = ctxr[3] * inv;
  ob.x = ctxr[4] * inv; ob.y = ctxr[5] * inv; ob.z = ctxr[6] * inv; ob.w = ctxr[7] * inv;
  *(float4*)op = oa;
  *(float4*)(op + 4) = ob;
}

extern "C" void kernel_launch(void* const* d_in, const int* in_sizes, int n_in,
                              void* d_out, int out_size, void* d_ws, size_t ws_size,
                              hipStream_t stream) {
  const float* input    = (const float*)d_in[0];
  const float* mask     = (const float*)d_in[1];
  const float* norm_w   = (const float*)d_in[2];
  const float* norm_b   = (const float*)d_in[3];
  const float* qkv_w    = (const float*)d_in[4];
  const float* qkv_b    = (const float*)d_in[5];
  const float* attn_ow  = (const float*)d_in[6];
  const float* attn_ob  = (const float*)d_in[7];
  const float* attn_nw  = (const float*)d_in[8];
  const float* attn_nb  = (const float*)d_in[9];
  const float* inter_w  = (const float*)d_in[10];
  const float* inter_b  = (const float*)d_in[11];
  const float* output_w = (const float*)d_in[12];
  const float* output_b = (const float*)d_in[13];

  const size_t SZ = (size_t)BB * SS * HH;  // 8,388,608
  // Aliased layout: total 6*SZ floats = 201 MB
  //   [0,SZ)        x_ln, later reused as y_ln
  //   [SZ,4SZ)      qkv   (dead after attention) -- also start of act
  //   [4SZ,5SZ)     ctx   (dead after attn proj) -- act overlaps this too
  //   [5SZ,6SZ)     attn_out
  float* ws = (float*)d_ws;
  if (ws_size < (size_t)(6 * SZ) * sizeof(float)) return;  // insufficient scratch
  float* x_ln     = ws;
  float* qkvb     = ws + SZ;
  float* ctxb     = ws + 4 * SZ;
  float* attn_out = ws + 5 * SZ;
  float* act      = ws + SZ;  // 4*SZ floats, overlaps dead qkv+ctx

  const int M = BB * SS;  // 8192

  // 1. x_ln = LN(input)
  ln_kernel<<<M, 256, 0, stream>>>(input, norm_w, norm_b, x_ln);
  // 2. qkv = x_ln @ qkv_w + qkv_b   (8192 x 3072 x 1024)
  gemm_kernel<0><<<dim3(3 * HH / 64, M / 64), 256, 0, stream>>>(
      x_ln, qkv_w, qkv_b, nullptr, qkvb, M, 3 * HH, HH);
  // 3. ctx = flash-attention(qkv, mask)
  attn_kernel<<<dim3(SS / 32, NHEADS, BB), 256, 0, stream>>>(qkvb, mask, ctxb);
  // 4. attn_out = ctx @ attn_ow + attn_ob + input
  gemm_kernel<2><<<dim3(HH / 64, M / 64), 256, 0, stream>>>(
      ctxb, attn_ow, attn_ob, input, attn_out, M, HH, HH);
  // 5. y_ln = LN(attn_out)
  ln_kernel<<<M, 256, 0, stream>>>(attn_out, attn_nw, attn_nb, x_ln);
  // 6. act = gelu(y_ln @ inter_w + inter_b)   (8192 x 4096 x 1024)
  gemm_kernel<1><<<dim3(DFF_ / 64, M / 64), 256, 0, stream>>>(
      x_ln, inter_w, inter_b, nullptr, act, M, DFF_, HH);
  // 7. out = act @ output_w + output_b + attn_out   (8192 x 1024 x 4096)
  gemm_kernel<2><<<dim3(HH / 64, M / 64), 256, 0, stream>>>(
      act, output_w, output_b, attn_out, (float*)d_out, M, HH, DFF_);
}

// Round 2
// 625.604 us; speedup vs baseline: 7.4138x; 7.4138x over previous
//
#include <hip/hip_runtime.h>
#include <math.h>

typedef __bf16 bf16_t;
typedef bf16_t bf16x8 __attribute__((ext_vector_type(8)));
typedef bf16_t bf16x4 __attribute__((ext_vector_type(4)));
typedef float f32x4 __attribute__((ext_vector_type(4)));

#define BB 4
#define SS 2048
#define HD1 1024
#define NH 16
#define DFF_ 4096

// ---------------- LayerNorm: fp32 in -> bf16 out, one block per row ---------
__device__ __forceinline__ float block_reduce_sum(float v, float* red) {
  const int lane = threadIdx.x & 63;
  const int wid = threadIdx.x >> 6;
#pragma unroll
  for (int off = 32; off > 0; off >>= 1) v += __shfl_down(v, off, 64);
  if (lane == 0) red[wid] = v;
  __syncthreads();
  float s = red[0] + red[1] + red[2] + red[3];
  __syncthreads();
  return s;
}

__global__ __launch_bounds__(256) void ln_kernel(const float* __restrict__ x,
                                                 const float* __restrict__ w,
                                                 const float* __restrict__ bv,
                                                 bf16_t* __restrict__ out) {
  __shared__ float red[4];
  const size_t row = blockIdx.x;
  const float4 xv = *(const float4*)(x + row * HD1 + threadIdx.x * 4);
  float s = xv.x + xv.y + xv.z + xv.w;
  s = block_reduce_sum(s, red);
  const float mu = s * (1.0f / HD1);
  float4 d;
  d.x = xv.x - mu; d.y = xv.y - mu; d.z = xv.z - mu; d.w = xv.w - mu;
  float sq = d.x * d.x + d.y * d.y + d.z * d.z + d.w * d.w;
  sq = block_reduce_sum(sq, red);
  const float rs = rsqrtf(sq * (1.0f / HD1) + 1e-12f);
  const float4 wv = *(const float4*)(w + threadIdx.x * 4);
  const float4 bb = *(const float4*)(bv + threadIdx.x * 4);
  bf16x4 o;
  o[0] = (bf16_t)(d.x * rs * wv.x + bb.x);
  o[1] = (bf16_t)(d.y * rs * wv.y + bb.y);
  o[2] = (bf16_t)(d.z * rs * wv.z + bb.z);
  o[3] = (bf16_t)(d.w * rs * wv.w + bb.w);
  *(bf16x4*)(out + row * HD1 + threadIdx.x * 4) = o;
}

// ---------------- Weight convert+transpose: W[K][N] f32 -> Wt[N][K] bf16 ----
__global__ __launch_bounds__(256) void wt_kernel(const float* __restrict__ W,
                                                 bf16_t* __restrict__ Wt,
                                                 int K, int N) {
  __shared__ bf16_t T[32][33];
  const int t = threadIdx.x;
  const int n0 = blockIdx.x * 32, k0 = blockIdx.y * 32;
  const int a = t >> 5, c = t & 31;
#pragma unroll
  for (int i = 0; i < 4; ++i) {
    const int kl = a + i * 8;
    T[kl][c] = (bf16_t)W[(size_t)(k0 + kl) * N + n0 + c];
  }
  __syncthreads();
#pragma unroll
  for (int i = 0; i < 4; ++i) {
    const int nl = a + i * 8;
    Wt[(size_t)(n0 + nl) * K + k0 + c] = T[c][nl];
  }
}

// ---------------- V transpose: qkv[b][s][2H + h*64 + d] -> Vt[b][h][d][s] ---
__global__ __launch_bounds__(256) void vtrans_kernel(const bf16_t* __restrict__ qkv,
                                                     bf16_t* __restrict__ Vt) {
  const int t = threadIdx.x;
  const int s = blockIdx.x * 256 + t;
  const int head = blockIdx.y, b = blockIdx.z;
  const bf16_t* src = qkv + (size_t)(b * SS + s) * 3072 + 2048 + head * 64;
  bf16_t* dst = Vt + ((size_t)(b * NH + head) * 64) * SS + s;
#pragma unroll
  for (int j = 0; j < 8; ++j) {
    bf16x8 v = *(const bf16x8*)(src + j * 8);
#pragma unroll
    for (int e = 0; e < 8; ++e) dst[(size_t)(j * 8 + e) * SS] = v[e];
  }
}

// ---------------- MFMA GEMM: C[M][N] = A[M][K] @ Wt[N][K]^T + epilogue ------
// EPI: 0=bias, 1=bias+exact GELU, 2=bias+residual(f32).  OBF: bf16 output.
template <int EPI, bool OBF>
__global__ __launch_bounds__(256) void gemm_bf16(
    const bf16_t* __restrict__ A, const bf16_t* __restrict__ Wt,
    const float* __restrict__ bias, const float* __restrict__ R,
    void* __restrict__ Cout, int M, int N, int K) {
  // padded stride 40 elems (80B = 20 words): 16-row frag reads spread all banks
  __shared__ bf16_t As[128 * 40];
  __shared__ bf16_t Bs[128 * 40];
  const int tid = threadIdx.x;
  const int lane = tid & 63;
  const int w = tid >> 6;
  const int wm = (w >> 1) * 64, wn = (w & 1) * 64;
  const int m0 = blockIdx.y * 128, n0 = blockIdx.x * 128;
  const int l15 = lane & 15, l4 = lane >> 4;

  const int arow = tid >> 2;
  const int akof = (tid & 3) * 8;
  const bf16_t* Ap = A + (size_t)(m0 + arow) * K + akof;
  const bf16_t* Bp = Wt + (size_t)(n0 + arow) * K + akof;
  bf16_t* Asw = As + arow * 40 + akof;
  bf16_t* Bsw = Bs + arow * 40 + akof;

  f32x4 acc[4][4] = {};

  for (int kt = 0; kt < K; kt += 32) {
    bf16x8 a0 = *(const bf16x8*)(Ap);
    bf16x8 a1 = *(const bf16x8*)(Ap + (size_t)64 * K);
    bf16x8 b0 = *(const bf16x8*)(Bp);
    bf16x8 b1 = *(const bf16x8*)(Bp + (size_t)64 * K);
    __syncthreads();  // previous tile's readers done
    *(bf16x8*)(Asw) = a0;
    *(bf16x8*)(Asw + 64 * 40) = a1;
    *(bf16x8*)(Bsw) = b0;
    *(bf16x8*)(Bsw + 64 * 40) = b1;
    __syncthreads();  // staging visible
    bf16x8 af[4], bfr[4];
#pragma unroll
    for (int i = 0; i < 4; ++i)
      af[i] = *(const bf16x8*)(As + (wm + i * 16 + l15) * 40 + l4 * 8);
#pragma unroll
    for (int j = 0; j < 4; ++j)
      bfr[j] = *(const bf16x8*)(Bs + (wn + j * 16 + l15) * 40 + l4 * 8);
#pragma unroll
    for (int i = 0; i < 4; ++i)
#pragma unroll
      for (int j = 0; j < 4; ++j)
        acc[i][j] = __builtin_amdgcn_mfma_f32_16x16x32_bf16(af[i], bfr[j],
                                                            acc[i][j], 0, 0, 0);
    Ap += 32;
    Bp += 32;
  }
#pragma unroll
  for (int j = 0; j < 4; ++j) {
    const int gn = n0 + wn + j * 16 + l15;
    const float bj = bias[gn];
#pragma unroll
    for (int i = 0; i < 4; ++i) {
      const int gm = m0 + wm + i * 16 + l4 * 4;
#pragma unroll
      for (int r = 0; r < 4; ++r) {
        float v = acc[i][j][r] + bj;
        if (EPI == 1) v = 0.5f * v * (1.0f + erff(v * 0.70710678118654752440f));
        if (EPI == 2) v += R[(size_t)(gm + r) * N + gn];
        if (OBF)
          ((bf16_t*)Cout)[(size_t)(gm + r) * N + gn] = (bf16_t)v;
        else
          ((float*)Cout)[(size_t)(gm + r) * N + gn] = v;
      }
    }
  }
}

// ---------------- MFMA flash attention: 64 q-rows/block, KVB=64 -------------
__global__ __launch_bounds__(256) void attn_kernel(
    const bf16_t* __restrict__ qkv, const bf16_t* __restrict__ Vt,
    const float* __restrict__ mask, bf16_t* __restrict__ ctx) {
  __shared__ bf16_t K_lds[64 * 72];  // [kv][hd], padded 72 (144B rows)
  __shared__ bf16_t V_lds[64 * 72];  // [hd][kv], padded 72
  __shared__ bf16_t P_lds[4][16 * 72];  // per-wave [q][kv]
  const int tid = threadIdx.x;
  const int lane = tid & 63;
  const int w = tid >> 6;
  const int l15 = lane & 15, l4 = lane >> 4;
  const int q0 = blockIdx.x * 64;
  const int head = blockIdx.y;
  const int b = blockIdx.z;

  // Q fragments in registers (A-operand: lane holds Q[l15][l4*8 + j (+32ks)])
  const size_t qoff =
      (size_t)(b * SS + q0 + w * 16 + l15) * 3072 + head * 64 + l4 * 8;
  const bf16x8 qf0 = *(const bf16x8*)(qkv + qoff);
  const bf16x8 qf1 = *(const bf16x8*)(qkv + qoff + 32);

  const int srow = tid >> 3;
  const int scol = (tid & 7) * 8;
  const bf16_t* Kp =
      qkv + (size_t)(b * SS + srow) * 3072 + 1024 + head * 64 + scol;
  const bf16_t* Vp =
      Vt + ((size_t)(b * NH + head) * 64 + srow) * SS + scol;

  float mrow[4], lrow[4];
  f32x4 cacc[4] = {};
#pragma unroll
  for (int r = 0; r < 4; ++r) { mrow[r] = -3.0e38f; lrow[r] = 0.0f; }

  for (int kv0 = 0; kv0 < SS; kv0 += 64) {
    // issue staging loads early (overlap with barrier wait)
    const bf16x8 k0 = *(const bf16x8*)(Kp + (size_t)kv0 * 3072);
    const bf16x8 k1 = *(const bf16x8*)(Kp + (size_t)(kv0 + 32) * 3072);
    const bf16x8 v0 = *(const bf16x8*)(Vp + kv0);
    const bf16x8 v1 = *(const bf16x8*)(Vp + (size_t)32 * SS + kv0);
    __syncthreads();  // all waves done reading previous K/V tile
    *(bf16x8*)(K_lds + srow * 72 + scol) = k0;
    *(bf16x8*)(K_lds + (srow + 32) * 72 + scol) = k1;
    *(bf16x8*)(V_lds + srow * 72 + scol) = v0;
    *(bf16x8*)(V_lds + (srow + 32) * 72 + scol) = v1;
    __syncthreads();

    // scores: S[q][kv] = Q @ K^T, 4 n-tiles x 2 k-steps
    f32x4 sacc[4] = {};
#pragma unroll
    for (int jn = 0; jn < 4; ++jn) {
      const bf16x8 kf0 = *(const bf16x8*)(K_lds + (jn * 16 + l15) * 72 + l4 * 8);
      const bf16x8 kf1 =
          *(const bf16x8*)(K_lds + (jn * 16 + l15) * 72 + 32 + l4 * 8);
      sacc[jn] = __builtin_amdgcn_mfma_f32_16x16x32_bf16(qf0, kf0, sacc[jn], 0, 0, 0);
      sacc[jn] = __builtin_amdgcn_mfma_f32_16x16x32_bf16(qf1, kf1, sacc[jn], 0, 0, 0);
    }
    float mval[4];
#pragma unroll
    for (int jn = 0; jn < 4; ++jn)
      mval[jn] = mask[(size_t)b * SS + kv0 + jn * 16 + l15];

    // online softmax; lane owns rows (l4*4 + r), cols (jn*16 + l15)
#pragma unroll
    for (int r = 0; r < 4; ++r) {
      float s0 = sacc[0][r] * 0.125f + mval[0];
      float s1 = sacc[1][r] * 0.125f + mval[1];
      float s2 = sacc[2][r] * 0.125f + mval[2];
      float s3 = sacc[3][r] * 0.125f + mval[3];
      float tm = fmaxf(fmaxf(s0, s1), fmaxf(s2, s3));
      tm = fmaxf(tm, __shfl_xor(tm, 1, 64));
      tm = fmaxf(tm, __shfl_xor(tm, 2, 64));
      tm = fmaxf(tm, __shfl_xor(tm, 4, 64));
      tm = fmaxf(tm, __shfl_xor(tm, 8, 64));
      const float mn = fmaxf(mrow[r], tm);
      const float sc = __expf(mrow[r] - mn);
      mrow[r] = mn;
      const float p0 = __expf(s0 - mn), p1 = __expf(s1 - mn);
      const float p2 = __expf(s2 - mn), p3 = __expf(s3 - mn);
      float ps = p0 + p1 + p2 + p3;
      ps += __shfl_xor(ps, 1, 64);
      ps += __shfl_xor(ps, 2, 64);
      ps += __shfl_xor(ps, 4, 64);
      ps += __shfl_xor(ps, 8, 64);
      lrow[r] = lrow[r] * sc + ps;
#pragma unroll
      for (int jh = 0; jh < 4; ++jh) cacc[jh][r] *= sc;
      const int qr = l4 * 4 + r;
      P_lds[w][qr * 72 + 0 + l15] = (bf16_t)p0;
      P_lds[w][qr * 72 + 16 + l15] = (bf16_t)p1;
      P_lds[w][qr * 72 + 32 + l15] = (bf16_t)p2;
      P_lds[w][qr * 72 + 48 + l15] = (bf16_t)p3;
    }
    // PV: ctx[q][hd] += P @ V
#pragma unroll
    for (int ks = 0; ks < 2; ++ks) {
      const bf16x8 pf =
          *(const bf16x8*)(&P_lds[w][l15 * 72 + ks * 32 + l4 * 8]);
#pragma unroll
      for (int jh = 0; jh < 4; ++jh) {
        const bf16x8 vf =
            *(const bf16x8*)(V_lds + (jh * 16 + l15) * 72 + ks * 32 + l4 * 8);
        cacc[jh] = __builtin_amdgcn_mfma_f32_16x16x32_bf16(pf, vf, cacc[jh], 0, 0, 0);
      }
    }
  }
#pragma unroll
  for (int r = 0; r < 4; ++r) {
    const float inv = 1.0f / lrow[r];
    const size_t row =
        (size_t)(b * SS + q0 + w * 16 + l4 * 4 + r) * 1024 + head * 64;
#pragma unroll
    for (int jh = 0; jh < 4; ++jh)
      ctx[row + jh * 16 + l15] = (bf16_t)(cacc[jh][r] * inv);
  }
}

extern "C" void kernel_launch(void* const* d_in, const int* in_sizes, int n_in,
                              void* d_out, int out_size, void* d_ws, size_t ws_size,
                              hipStream_t stream) {
  const float* input    = (const float*)d_in[0];
  const float* mask     = (const float*)d_in[1];
  const float* norm_w   = (const float*)d_in[2];
  const float* norm_b   = (const float*)d_in[3];
  const float* qkv_w    = (const float*)d_in[4];
  const float* qkv_b    = (const float*)d_in[5];
  const float* attn_ow  = (const float*)d_in[6];
  const float* attn_ob  = (const float*)d_in[7];
  const float* attn_nw  = (const float*)d_in[8];
  const float* attn_nb  = (const float*)d_in[9];
  const float* inter_w  = (const float*)d_in[10];
  const float* inter_b  = (const float*)d_in[11];
  const float* output_w = (const float*)d_in[12];
  const float* output_b = (const float*)d_in[13];

  // Workspace layout (bytes):
  //   [0,16M)    x_ln bf16            -- act aliases [0,64M) later
  //   [16M,64M)  qkv bf16
  //   [64M,80M)  Vt bf16
  //   [80M,96M)  ctx bf16, later y_ln
  //   [96M,128M) attn_out f32
  //   [128M+..)  transposed bf16 weights
  char* ws = (char*)d_ws;
  const size_t off_xln = 0;
  const size_t off_qkv = 16777216;
  const size_t off_vt  = 67108864;
  const size_t off_ctx = 83886080;
  const size_t off_ao  = 100663296;
  const size_t off_wq  = 134217728;
  const size_t off_wo  = 140509184;
  const size_t off_wi  = 142606336;
  const size_t off_w2  = 150994944;
  const size_t NEED    = 159383552;
  if (ws_size < NEED) return;

  bf16_t* x_ln  = (bf16_t*)(ws + off_xln);
  bf16_t* qkvb  = (bf16_t*)(ws + off_qkv);
  bf16_t* VtB   = (bf16_t*)(ws + off_vt);
  bf16_t* ctxb  = (bf16_t*)(ws + off_ctx);
  bf16_t* y_ln  = (bf16_t*)(ws + off_ctx);
  float*  a_out = (float*)(ws + off_ao);
  bf16_t* wq_t  = (bf16_t*)(ws + off_wq);
  bf16_t* wo_t  = (bf16_t*)(ws + off_wo);
  bf16_t* wi_t  = (bf16_t*)(ws + off_wi);
  bf16_t* w2_t  = (bf16_t*)(ws + off_w2);
  bf16_t* act   = (bf16_t*)(ws + off_xln);  // aliases x_ln+qkv (both dead)

  const int M = BB * SS;  // 8192

  // weight convert+transpose
  wt_kernel<<<dim3(3072 / 32, 1024 / 32), 256, 0, stream>>>(qkv_w, wq_t, 1024, 3072);
  wt_kernel<<<dim3(1024 / 32, 1024 / 32), 256, 0, stream>>>(attn_ow, wo_t, 1024, 1024);
  wt_kernel<<<dim3(4096 / 32, 1024 / 32), 256, 0, stream>>>(inter_w, wi_t, 1024, 4096);
  wt_kernel<<<dim3(1024 / 32, 4096 / 32), 256, 0, stream>>>(output_w, w2_t, 4096, 1024);

  // 1. x_ln = LN(input)
  ln_kernel<<<M, 256, 0, stream>>>(input, norm_w, norm_b, x_ln);
  // 2. qkv = x_ln @ qkv_w + b
  gemm_bf16<0, true><<<dim3(3072 / 128, M / 128), 256, 0, stream>>>(
      x_ln, wq_t, qkv_b, nullptr, qkvb, M, 3072, 1024);
  // 3. Vt = transpose(V)
  vtrans_kernel<<<dim3(SS / 256, NH, BB), 256, 0, stream>>>(qkvb, VtB);
  // 4. ctx = flash-attention
  attn_kernel<<<dim3(SS / 64, NH, BB), 256, 0, stream>>>(qkvb, VtB, mask, ctxb);
  // 5. attn_out = ctx @ attn_ow + b + input
  gemm_bf16<2, false><<<dim3(1024 / 128, M / 128), 256, 0, stream>>>(
      ctxb, wo_t, attn_ob, input, a_out, M, 1024, 1024);
  // 6. y_ln = LN(attn_out)
  ln_kernel<<<M, 256, 0, stream>>>(a_out, attn_nw, attn_nb, y_ln);
  // 7. act = gelu(y_ln @ inter_w + b)
  gemm_bf16<1, true><<<dim3(4096 / 128, M / 128), 256, 0, stream>>>(
      y_ln, wi_t, inter_b, nullptr, act, M, 4096, 1024);
  // 8. out = act @ output_w + b + attn_out
  gemm_bf16<2, false><<<dim3(1024 / 128, M / 128), 256, 0, stream>>>(
      act, w2_t, output_b, a_out, (float*)d_out, M, 1024, 4096);
}

// Round 3
// 531.326 us; speedup vs baseline: 8.7293x; 1.1774x over previous
//
#include <hip/hip_runtime.h>
#include <math.h>

typedef __bf16 bf16_t;
typedef bf16_t bf16x8 __attribute__((ext_vector_type(8)));
typedef bf16_t bf16x4 __attribute__((ext_vector_type(4)));
typedef float f32x4 __attribute__((ext_vector_type(4)));
typedef float f32x16 __attribute__((ext_vector_type(16)));

#define BB 4
#define SS 2048
#define HD1 1024
#define NH 16
#define DFF_ 4096

__device__ __forceinline__ void gload_lds16(const bf16_t* g, bf16_t* l) {
  __builtin_amdgcn_global_load_lds(
      (const __attribute__((address_space(1))) void*)g,
      (__attribute__((address_space(3))) void*)l, 16, 0, 0);
}

__device__ __forceinline__ unsigned pack2_bf16(float a, float b) {
  union { bf16_t h[2]; unsigned u; } cv;
  cv.h[0] = (bf16_t)a;
  cv.h[1] = (bf16_t)b;
  return cv.u;
}

// ---------------- LayerNorm: fp32 in -> bf16 out, one block per row ---------
__device__ __forceinline__ float block_reduce_sum(float v, float* red) {
  const int lane = threadIdx.x & 63;
  const int wid = threadIdx.x >> 6;
#pragma unroll
  for (int off = 32; off > 0; off >>= 1) v += __shfl_down(v, off, 64);
  if (lane == 0) red[wid] = v;
  __syncthreads();
  float s = red[0] + red[1] + red[2] + red[3];
  __syncthreads();
  return s;
}

__global__ __launch_bounds__(256) void ln_kernel(const float* __restrict__ x,
                                                 const float* __restrict__ w,
                                                 const float* __restrict__ bv,
                                                 bf16_t* __restrict__ out) {
  __shared__ float red[4];
  const size_t row = blockIdx.x;
  const float4 xv = *(const float4*)(x + row * HD1 + threadIdx.x * 4);
  float s = xv.x + xv.y + xv.z + xv.w;
  s = block_reduce_sum(s, red);
  const float mu = s * (1.0f / HD1);
  float4 d;
  d.x = xv.x - mu; d.y = xv.y - mu; d.z = xv.z - mu; d.w = xv.w - mu;
  float sq = d.x * d.x + d.y * d.y + d.z * d.z + d.w * d.w;
  sq = block_reduce_sum(sq, red);
  const float rs = rsqrtf(sq * (1.0f / HD1) + 1e-12f);
  const float4 wv = *(const float4*)(w + threadIdx.x * 4);
  const float4 bb = *(const float4*)(bv + threadIdx.x * 4);
  bf16x4 o;
  o[0] = (bf16_t)(d.x * rs * wv.x + bb.x);
  o[1] = (bf16_t)(d.y * rs * wv.y + bb.y);
  o[2] = (bf16_t)(d.z * rs * wv.z + bb.z);
  o[3] = (bf16_t)(d.w * rs * wv.w + bb.w);
  *(bf16x4*)(out + row * HD1 + threadIdx.x * 4) = o;
}

// ---------------- Weight convert+transpose: W[K][N] f32 -> Wt[N][K] bf16 ----
__global__ __launch_bounds__(256) void wt_kernel(const float* __restrict__ W,
                                                 bf16_t* __restrict__ Wt,
                                                 int K, int N) {
  __shared__ bf16_t T[32][33];
  const int t = threadIdx.x;
  const int n0 = blockIdx.x * 32, k0 = blockIdx.y * 32;
  const int a = t >> 5, c = t & 31;
#pragma unroll
  for (int i = 0; i < 4; ++i) {
    const int kl = a + i * 8;
    T[kl][c] = (bf16_t)W[(size_t)(k0 + kl) * N + n0 + c];
  }
  __syncthreads();
#pragma unroll
  for (int i = 0; i < 4; ++i) {
    const int nl = a + i * 8;
    Wt[(size_t)(n0 + nl) * K + k0 + c] = T[c][nl];
  }
}

// ---------------- V transpose: qkv[b][s][2H + h*64 + d] -> Vt[b][h][d][s] ---
__global__ __launch_bounds__(256) void vtrans_kernel(const bf16_t* __restrict__ qkv,
                                                     bf16_t* __restrict__ Vt) {
  const int t = threadIdx.x;
  const int s = blockIdx.x * 256 + t;
  const int head = blockIdx.y, b = blockIdx.z;
  const bf16_t* src = qkv + (size_t)(b * SS + s) * 3072 + 2048 + head * 64;
  bf16_t* dst = Vt + ((size_t)(b * NH + head) * 64) * SS + s;
#pragma unroll
  for (int j = 0; j < 8; ++j) {
    bf16x8 v = *(const bf16x8*)(src + j * 8);
#pragma unroll
    for (int e = 0; e < 8; ++e) dst[(size_t)(j * 8 + e) * SS] = v[e];
  }
}

// ---------------- MFMA GEMM (m97 structure): C = A @ Wt^T + epilogue --------
// EPI: 0=bias, 1=bias+exact GELU, 2=bias+residual(f32).  OBF: bf16 output.
template <int EPI, bool OBF>
__global__ __launch_bounds__(256) void gemm_bf16(
    const bf16_t* __restrict__ A, const bf16_t* __restrict__ Wt,
    const float* __restrict__ bias, const float* __restrict__ R,
    void* __restrict__ Cout, int M, int N, int K) {
  __shared__ __align__(16) bf16_t As[128 * 32];
  __shared__ __align__(16) bf16_t Bs[128 * 32];
  const int tid = threadIdx.x;
  const int lane = tid & 63;
  const int w = tid >> 6;
  const int wm = (w >> 1) * 64, wn = (w & 1) * 64;
  const int m0 = blockIdx.y * 128, n0 = blockIdx.x * 128;
  const int l15 = lane & 15, l4 = lane >> 4;

  const int arow = tid >> 2;
  const int akof = (tid & 3) * 8;
  const bf16_t* Ap = A + (size_t)(m0 + arow) * K + akof;
  const bf16_t* Bp = Wt + (size_t)(n0 + arow) * K + akof;
  // wave-uniform LDS bases: lane l writes base + l*16B (verified mapping)
  bf16_t* dstA = As + w * 512;
  bf16_t* dstB = Bs + w * 512;

  f32x4 acc[4][4] = {};

  for (int kt = 0; kt < K; kt += 32) {
    __syncthreads();  // previous tile's readers done
    gload_lds16(Ap, dstA);
    gload_lds16(Ap + (size_t)64 * K, dstA + 2048);
    gload_lds16(Bp, dstB);
    gload_lds16(Bp + (size_t)64 * K, dstB + 2048);
    __syncthreads();  // implicit vmcnt drain
    bf16x8 af[4], bfr[4];
#pragma unroll
    for (int i = 0; i < 4; ++i)
      af[i] = *(const bf16x8*)(As + (wm + i * 16 + l15) * 32 + l4 * 8);
#pragma unroll
    for (int j = 0; j < 4; ++j)
      bfr[j] = *(const bf16x8*)(Bs + (wn + j * 16 + l15) * 32 + l4 * 8);
#pragma unroll
    for (int i = 0; i < 4; ++i)
#pragma unroll
      for (int j = 0; j < 4; ++j)
        acc[i][j] = __builtin_amdgcn_mfma_f32_16x16x32_bf16(af[i], bfr[j],
                                                            acc[i][j], 0, 0, 0);
    Ap += 32;
    Bp += 32;
  }
#pragma unroll
  for (int j = 0; j < 4; ++j) {
    const int gn = n0 + wn + j * 16 + l15;
    const float bj = bias[gn];
#pragma unroll
    for (int i = 0; i < 4; ++i) {
      const int gm = m0 + wm + i * 16 + l4 * 4;
#pragma unroll
      for (int r = 0; r < 4; ++r) {
        float v = acc[i][j][r] + bj;
        if (EPI == 1) v = 0.5f * v * (1.0f + erff(v * 0.70710678118654752440f));
        if (EPI == 2) v += R[(size_t)(gm + r) * N + gn];
        if (OBF)
          ((bf16_t*)Cout)[(size_t)(gm + r) * N + gn] = (bf16_t)v;
        else
          ((float*)Cout)[(size_t)(gm + r) * N + gn] = v;
      }
    }
  }
}

// ---------------- MFMA flash attention, swapped 32x32x16 structure ----------
// Block: 4 waves x 32 q-rows = 128 q. KV tile = 64.
// S^T = mfma(K, Q^T): lane owns q = lane&31; kv rows spread over regs.
// P stays in registers (bf16 pack + half-wave shfl exchange) -> PV directly.
__global__ __launch_bounds__(256, 2) void attn_kernel(
    const bf16_t* __restrict__ qkv, const bf16_t* __restrict__ Vt,
    const float* __restrict__ mask, bf16_t* __restrict__ ctx) {
  __shared__ __align__(16) bf16_t K_lds[64 * 72];   // [kv][d]
  __shared__ __align__(16) bf16_t Vt_lds[64 * 72];  // [dv][kv]
  const int tid = threadIdx.x;
  const int lane = tid & 63;
  const int w = tid >> 6;
  const int l31 = lane & 31;
  const int h = lane >> 5;
  const int q0 = blockIdx.x * 128;
  const int head = blockIdx.y;
  const int b = blockIdx.z;
  const int qrow = q0 + w * 32 + l31;

  // Q as B-operand: qf[ks] = Q[q=l31][d = 16ks + 8h + j], j=0..7
  bf16x8 qf[4];
  {
    const bf16_t* qp = qkv + (size_t)(b * SS + qrow) * 3072 + head * 64 + 8 * h;
#pragma unroll
    for (int ks = 0; ks < 4; ++ks) qf[ks] = *(const bf16x8*)(qp + 16 * ks);
  }

  const int srow = tid >> 2;          // staging row 0..63
  const int scol = (tid & 3) * 16;    // staging col 0..48

  float m = -3.0e38f, l = 0.0f;
  f32x16 cacc0 = {};  // ctx[q][dv=l31]
  f32x16 cacc1 = {};  // ctx[q][dv=l31+32]

  for (int kv0 = 0; kv0 < SS; kv0 += 64) {
    const bf16_t* kp =
        qkv + (size_t)(b * SS + kv0 + srow) * 3072 + 1024 + head * 64 + scol;
    const bf16_t* vp =
        Vt + ((size_t)(b * NH + head) * 64 + srow) * SS + kv0 + scol;
    const bf16x8 k0 = *(const bf16x8*)kp;
    const bf16x8 k1 = *(const bf16x8*)(kp + 8);
    const bf16x8 v0 = *(const bf16x8*)vp;
    const bf16x8 v1 = *(const bf16x8*)(vp + 8);
    float4 mv[8];
#pragma unroll
    for (int k2 = 0; k2 < 8; ++k2)
      mv[k2] = *(const float4*)(mask + (size_t)b * SS + kv0 + 8 * k2 + 4 * h);
    __syncthreads();  // previous tile's LDS readers done
    *(bf16x8*)(K_lds + srow * 72 + scol) = k0;
    *(bf16x8*)(K_lds + srow * 72 + scol + 8) = k1;
    *(bf16x8*)(Vt_lds + srow * 72 + scol) = v0;
    *(bf16x8*)(Vt_lds + srow * 72 + scol + 8) = v1;
    __syncthreads();

    // ---- QK^T: sacc[sub] = S^T tile; rows kv = (r&3)+8*(r>>2)+4h+32*sub,
    //      col q = l31
    f32x16 sacc0 = {};
    f32x16 sacc1 = {};
#pragma unroll
    for (int ks = 0; ks < 4; ++ks) {
      const bf16x8 kf0 = *(const bf16x8*)(K_lds + l31 * 72 + 16 * ks + 8 * h);
      const bf16x8 kf1 =
          *(const bf16x8*)(K_lds + (l31 + 32) * 72 + 16 * ks + 8 * h);
      sacc0 = __builtin_amdgcn_mfma_f32_32x32x16_bf16(kf0, qf[ks], sacc0, 0, 0, 0);
      sacc1 = __builtin_amdgcn_mfma_f32_32x32x16_bf16(kf1, qf[ks], sacc1, 0, 0, 0);
    }

    // ---- online softmax (lane owns q = l31; 32 kv values split over halves)
    float ps[32];
    float tmax = -3.0e38f;
#pragma unroll
    for (int r = 0; r < 16; ++r) {
      const float s0 = sacc0[r] * 0.125f + mv[(r >> 2)][r & 3];
      const float s1 = sacc1[r] * 0.125f + mv[(r >> 2) + 4][r & 3];
      ps[r] = s0;
      ps[16 + r] = s1;
      tmax = fmaxf(tmax, fmaxf(s0, s1));
    }
    tmax = fmaxf(tmax, __shfl_xor(tmax, 32, 64));
    if (__any(tmax > m + 8.0f)) {  // defer-max (T13)
      const float mnew = fmaxf(m, tmax);
      const float sc = __expf(m - mnew);
      m = mnew;
      l *= sc;
#pragma unroll
      for (int r = 0; r < 16; ++r) {
        const float scr = __shfl(sc, (r & 3) + 8 * (r >> 2) + 4 * h, 64);
        cacc0[r] *= scr;
        cacc1[r] *= scr;
      }
    }
    float ls = 0.0f;
#pragma unroll
    for (int i = 0; i < 32; ++i) {
      ps[i] = __expf(ps[i] - m);
      ls += ps[i];
    }
    l += ls + __shfl_xor(ls, 32, 64);

    // ---- pack P to bf16 words: w0/w1[k] cover kv = 8k + 4h + {0..3}
    unsigned pw0[8], pw1[8];
#pragma unroll
    for (int k = 0; k < 8; ++k) {
      const int base = (k >> 2) * 16 + (k & 3) * 4;
      pw0[k] = pack2_bf16(ps[base + 0], ps[base + 1]);
      pw1[k] = pack2_bf16(ps[base + 2], ps[base + 3]);
    }
    // ---- half-exchange + PV MFMAs (A = P[q=l31][kv local 8h+j])
#pragma unroll
    for (int t = 0; t < 4; ++t) {
      const unsigned e0 = h ? pw0[2 * t] : pw0[2 * t + 1];
      const unsigned e1 = h ? pw1[2 * t] : pw1[2 * t + 1];
      const unsigned o0 = (unsigned)__shfl_xor((int)e0, 32, 64);
      const unsigned o1 = (unsigned)__shfl_xor((int)e1, 32, 64);
      const unsigned a0 = h ? pw0[2 * t + 1] : pw0[2 * t];
      const unsigned a1 = h ? pw1[2 * t + 1] : pw1[2 * t];
      union { unsigned u[4]; bf16x8 v; } pu;
      pu.u[0] = h ? o0 : a0;
      pu.u[1] = h ? o1 : a1;
      pu.u[2] = h ? a0 : o0;
      pu.u[3] = h ? a1 : o1;
      const bf16x8 vf0 = *(const bf16x8*)(Vt_lds + l31 * 72 + 16 * t + 8 * h);
      const bf16x8 vf1 =
          *(const bf16x8*)(Vt_lds + (l31 + 32) * 72 + 16 * t + 8 * h);
      cacc0 = __builtin_amdgcn_mfma_f32_32x32x16_bf16(pu.v, vf0, cacc0, 0, 0, 0);
      cacc1 = __builtin_amdgcn_mfma_f32_32x32x16_bf16(pu.v, vf1, cacc1, 0, 0, 0);
    }
  }

  // ---- epilogue: normalize rows; cacc row q = (r&3)+8*(r>>2)+4h
  const float linv = 1.0f / l;
#pragma unroll
  for (int r = 0; r < 16; ++r) {
    const int rq = (r & 3) + 8 * (r >> 2) + 4 * h;
    const float li = __shfl(linv, rq, 64);
    const int grow = q0 + w * 32 + rq;
    bf16_t* op = ctx + (size_t)(b * SS + grow) * 1024 + head * 64 + l31;
    op[0] = (bf16_t)(cacc0[r] * li);
    op[32] = (bf16_t)(cacc1[r] * li);
  }
}

extern "C" void kernel_launch(void* const* d_in, const int* in_sizes, int n_in,
                              void* d_out, int out_size, void* d_ws, size_t ws_size,
                              hipStream_t stream) {
  const float* input    = (const float*)d_in[0];
  const float* mask     = (const float*)d_in[1];
  const float* norm_w   = (const float*)d_in[2];
  const float* norm_b   = (const float*)d_in[3];
  const float* qkv_w    = (const float*)d_in[4];
  const float* qkv_b    = (const float*)d_in[5];
  const float* attn_ow  = (const float*)d_in[6];
  const float* attn_ob  = (const float*)d_in[7];
  const float* attn_nw  = (const float*)d_in[8];
  const float* attn_nb  = (const float*)d_in[9];
  const float* inter_w  = (const float*)d_in[10];
  const float* inter_b  = (const float*)d_in[11];
  const float* output_w = (const float*)d_in[12];
  const float* output_b = (const float*)d_in[13];

  char* ws = (char*)d_ws;
  const size_t off_xln = 0;
  const size_t off_qkv = 16777216;
  const size_t off_vt  = 67108864;
  const size_t off_ctx = 83886080;
  const size_t off_ao  = 100663296;
  const size_t off_wq  = 134217728;
  const size_t off_wo  = 140509184;
  const size_t off_wi  = 142606336;
  const size_t off_w2  = 150994944;
  const size_t NEED    = 159383552;
  if (ws_size < NEED) return;

  bf16_t* x_ln  = (bf16_t*)(ws + off_xln);
  bf16_t* qkvb  = (bf16_t*)(ws + off_qkv);
  bf16_t* VtB   = (bf16_t*)(ws + off_vt);
  bf16_t* ctxb  = (bf16_t*)(ws + off_ctx);
  bf16_t* y_ln  = (bf16_t*)(ws + off_ctx);
  float*  a_out = (float*)(ws + off_ao);
  bf16_t* wq_t  = (bf16_t*)(ws + off_wq);
  bf16_t* wo_t  = (bf16_t*)(ws + off_wo);
  bf16_t* wi_t  = (bf16_t*)(ws + off_wi);
  bf16_t* w2_t  = (bf16_t*)(ws + off_w2);
  bf16_t* act   = (bf16_t*)(ws + off_xln);

  const int M = BB * SS;  // 8192

  wt_kernel<<<dim3(3072 / 32, 1024 / 32), 256, 0, stream>>>(qkv_w, wq_t, 1024, 3072);
  wt_kernel<<<dim3(1024 / 32, 1024 / 32), 256, 0, stream>>>(attn_ow, wo_t, 1024, 1024);
  wt_kernel<<<dim3(4096 / 32, 1024 / 32), 256, 0, stream>>>(inter_w, wi_t, 1024, 4096);
  wt_kernel<<<dim3(1024 / 32, 4096 / 32), 256, 0, stream>>>(output_w, w2_t, 4096, 1024);

  ln_kernel<<<M, 256, 0, stream>>>(input, norm_w, norm_b, x_ln);
  gemm_bf16<0, true><<<dim3(3072 / 128, M / 128), 256, 0, stream>>>(
      x_ln, wq_t, qkv_b, nullptr, qkvb, M, 3072, 1024);
  vtrans_kernel<<<dim3(SS / 256, NH, BB), 256, 0, stream>>>(qkvb, VtB);
  attn_kernel<<<dim3(SS / 128, NH, BB), 256, 0, stream>>>(qkvb, VtB, mask, ctxb);
  gemm_bf16<2, false><<<dim3(1024 / 128, M / 128), 256, 0, stream>>>(
      ctxb, wo_t, attn_ob, input, a_out, M, 1024, 1024);
  ln_kernel<<<M, 256, 0, stream>>>(a_out, attn_nw, attn_nb, y_ln);
  gemm_bf16<1, true><<<dim3(4096 / 128, M / 128), 256, 0, stream>>>(
      y_ln, wi_t, inter_b, nullptr, act, M, 4096, 1024);
  gemm_bf16<2, false><<<dim3(1024 / 128, M / 128), 256, 0, stream>>>(
      act, w2_t, output_b, a_out, (float*)d_out, M, 1024, 4096);
}

// Round 4
// 499.085 us; speedup vs baseline: 9.2932x; 1.0646x over previous
//
#include <hip/hip_runtime.h>
#include <math.h>

typedef __bf16 bf16_t;
typedef bf16_t bf16x8 __attribute__((ext_vector_type(8)));
typedef bf16_t bf16x4 __attribute__((ext_vector_type(4)));
typedef float f32x4 __attribute__((ext_vector_type(4)));
typedef float f32x16 __attribute__((ext_vector_type(16)));

#define BB 4
#define SS 2048
#define HD1 1024
#define NH 16
#define DFF_ 4096

__device__ __forceinline__ void gload_lds16(const bf16_t* g, bf16_t* l) {
  __builtin_amdgcn_global_load_lds(
      (const __attribute__((address_space(1))) void*)g,
      (__attribute__((address_space(3))) void*)l, 16, 0, 0);
}

__device__ __forceinline__ unsigned pack2_bf16(float a, float b) {
  union { bf16_t h[2]; unsigned u; } cv;
  cv.h[0] = (bf16_t)a;
  cv.h[1] = (bf16_t)b;
  return cv.u;
}

// ---------------- LayerNorm: fp32 in -> bf16 out, one block per row ---------
__device__ __forceinline__ float block_reduce_sum(float v, float* red) {
  const int lane = threadIdx.x & 63;
  const int wid = threadIdx.x >> 6;
#pragma unroll
  for (int off = 32; off > 0; off >>= 1) v += __shfl_down(v, off, 64);
  if (lane == 0) red[wid] = v;
  __syncthreads();
  float s = red[0] + red[1] + red[2] + red[3];
  __syncthreads();
  return s;
}

__global__ __launch_bounds__(256) void ln_kernel(const float* __restrict__ x,
                                                 const float* __restrict__ w,
                                                 const float* __restrict__ bv,
                                                 bf16_t* __restrict__ out) {
  __shared__ float red[4];
  const size_t row = blockIdx.x;
  const float4 xv = *(const float4*)(x + row * HD1 + threadIdx.x * 4);
  float s = xv.x + xv.y + xv.z + xv.w;
  s = block_reduce_sum(s, red);
  const float mu = s * (1.0f / HD1);
  float4 d;
  d.x = xv.x - mu; d.y = xv.y - mu; d.z = xv.z - mu; d.w = xv.w - mu;
  float sq = d.x * d.x + d.y * d.y + d.z * d.z + d.w * d.w;
  sq = block_reduce_sum(sq, red);
  const float rs = rsqrtf(sq * (1.0f / HD1) + 1e-12f);
  const float4 wv = *(const float4*)(w + threadIdx.x * 4);
  const float4 bb = *(const float4*)(bv + threadIdx.x * 4);
  bf16x4 o;
  o[0] = (bf16_t)(d.x * rs * wv.x + bb.x);
  o[1] = (bf16_t)(d.y * rs * wv.y + bb.y);
  o[2] = (bf16_t)(d.z * rs * wv.z + bb.z);
  o[3] = (bf16_t)(d.w * rs * wv.w + bb.w);
  *(bf16x4*)(out + row * HD1 + threadIdx.x * 4) = o;
}

// ---------------- Weight convert+transpose: W[K][N] f32 -> Wt[N][K] bf16 ----
__global__ __launch_bounds__(256) void wt_kernel(const float* __restrict__ W,
                                                 bf16_t* __restrict__ Wt,
                                                 int K, int N) {
  __shared__ bf16_t T[32][33];
  const int t = threadIdx.x;
  const int n0 = blockIdx.x * 32, k0 = blockIdx.y * 32;
  const int a = t >> 5, c = t & 31;
#pragma unroll
  for (int i = 0; i < 4; ++i) {
    const int kl = a + i * 8;
    T[kl][c] = (bf16_t)W[(size_t)(k0 + kl) * N + n0 + c];
  }
  __syncthreads();
#pragma unroll
  for (int i = 0; i < 4; ++i) {
    const int nl = a + i * 8;
    Wt[(size_t)(n0 + nl) * K + k0 + c] = T[c][nl];
  }
}

// ---------------- V transpose: qkv[b][s][2H + h*64 + d] -> Vt[b][h][d][s] ---
__global__ __launch_bounds__(256) void vtrans_kernel(const bf16_t* __restrict__ qkv,
                                                     bf16_t* __restrict__ Vt) {
  const int t = threadIdx.x;
  const int s = blockIdx.x * 256 + t;
  const int head = blockIdx.y, b = blockIdx.z;
  const bf16_t* src = qkv + (size_t)(b * SS + s) * 3072 + 2048 + head * 64;
  bf16_t* dst = Vt + ((size_t)(b * NH + head) * 64) * SS + s;
#pragma unroll
  for (int j = 0; j < 8; ++j) {
    bf16x8 v = *(const bf16x8*)(src + j * 8);
#pragma unroll
    for (int e = 0; e < 8; ++e) dst[(size_t)(j * 8 + e) * SS] = v[e];
  }
}

// ---------------- MFMA GEMM, BK=64 double-buffered 2-phase -------------------
// C[M][N] = A[M][K] @ Wt[N][K]^T + epilogue
// EPI: 0=bias, 1=bias+exact GELU, 2=bias+residual(f32).  OBF: bf16 output.
template <int EPI, bool OBF>
__global__ __launch_bounds__(256) void gemm_bf16(
    const bf16_t* __restrict__ A, const bf16_t* __restrict__ Wt,
    const float* __restrict__ bias, const float* __restrict__ R,
    void* __restrict__ Cout, int M, int N, int K) {
  __shared__ __align__(16) char smem[65536];
  bf16_t* As = (bf16_t*)smem;              // [2][128*64]
  bf16_t* Bs = (bf16_t*)(smem + 32768);    // [2][128*64]
  const int tid = threadIdx.x;
  const int lane = tid & 63;
  const int w = tid >> 6;
  const int wm = (w >> 1) * 64, wn = (w & 1) * 64;
  const int l15 = lane & 15, l4 = lane >> 4;

  // bijective XCD swizzle (all grids have nwg % 8 == 0)
  const int gx = gridDim.x;
  int id = blockIdx.x + gx * blockIdx.y;
  const int cpx = (gx * gridDim.y) >> 3;
  id = (id & 7) * cpx + (id >> 3);
  const int m0 = (id / gx) * 128;
  const int n0 = (id % gx) * 128;

  // staging geometry: chunk c = rows [c*32,(c+1)*32), thread covers
  // row c*32 + tid/8, cols (tid%8)*8 .. +8  (16B per lane)
  const int lrow = tid >> 3;
  const int lcol = (tid & 7) * 8;
  const bf16_t* Ag = A + (size_t)(m0 + lrow) * K + lcol;
  const bf16_t* Bg = Wt + (size_t)(n0 + lrow) * K + lcol;
  const size_t rstride = (size_t)32 * K;

  // prologue: stage tile 0 into buffer 0
#pragma unroll
  for (int c = 0; c < 4; ++c) {
    gload_lds16(Ag + c * rstride, As + c * 2048 + w * 512);
    gload_lds16(Bg + c * rstride, Bs + c * 2048 + w * 512);
  }

  const int NT = K >> 6;
  f32x4 acc[4][4] = {};

  for (int t = 0; t < NT; ++t) {
    const int cur = t & 1;
    __syncthreads();  // drains in-flight stage for buf[cur]; protects buf[cur^1]
    if (t + 1 < NT) {
      const bf16_t* Agn = Ag + (size_t)(t + 1) * 64;
      const bf16_t* Bgn = Bg + (size_t)(t + 1) * 64;
      bf16_t* Ad = As + (cur ^ 1) * 8192;
      bf16_t* Bd = Bs + (cur ^ 1) * 8192;
#pragma unroll
      for (int c = 0; c < 4; ++c) {
        gload_lds16(Agn + c * rstride, Ad + c * 2048 + w * 512);
        gload_lds16(Bgn + c * rstride, Bd + c * 2048 + w * 512);
      }
    }
    const bf16_t* Ab = As + cur * 8192;
    const bf16_t* Bb = Bs + cur * 8192;
    bf16x8 af[2][4], bfr[2][4];
#pragma unroll
    for (int ks = 0; ks < 2; ++ks) {
#pragma unroll
      for (int i = 0; i < 4; ++i)
        af[ks][i] =
            *(const bf16x8*)(Ab + (wm + i * 16 + l15) * 64 + ks * 32 + l4 * 8);
#pragma unroll
      for (int j = 0; j < 4; ++j)
        bfr[ks][j] =
            *(const bf16x8*)(Bb + (wn + j * 16 + l15) * 64 + ks * 32 + l4 * 8);
    }
#pragma unroll
    for (int ks = 0; ks < 2; ++ks)
#pragma unroll
      for (int i = 0; i < 4; ++i)
#pragma unroll
        for (int j = 0; j < 4; ++j)
          acc[i][j] = __builtin_amdgcn_mfma_f32_16x16x32_bf16(
              af[ks][i], bfr[ks][j], acc[i][j], 0, 0, 0);
  }

  if (OBF) {
    // stage C tile (f32) in LDS, re-read as rows -> coalesced bf16 stores
    __syncthreads();
    float* Cs = (float*)smem;  // 128 x 128 f32 = 64 KiB
#pragma unroll
    for (int j = 0; j < 4; ++j) {
      const float bj = bias[n0 + wn + j * 16 + l15];
#pragma unroll
      for (int i = 0; i < 4; ++i)
#pragma unroll
        for (int r = 0; r < 4; ++r) {
          float v = acc[i][j][r] + bj;
          if (EPI == 1)
            v = 0.5f * v * (1.0f + erff(v * 0.70710678118654752440f));
          Cs[(wm + i * 16 + l4 * 4 + r) * 128 + wn + j * 16 + l15] = v;
        }
    }
    __syncthreads();
    bf16_t* Cb = (bf16_t*)Cout;
#pragma unroll
    for (int p = 0; p < 16; ++p) {
      const int idx = p * 256 + tid;
      const int row = idx >> 5, c4 = idx & 31;
      const f32x4 v = *(const f32x4*)(Cs + row * 128 + c4 * 4);
      bf16x4 o;
      o[0] = (bf16_t)v[0]; o[1] = (bf16_t)v[1];
      o[2] = (bf16_t)v[2]; o[3] = (bf16_t)v[3];
      *(bf16x4*)(Cb + (size_t)(m0 + row) * N + n0 + c4 * 4) = o;
    }
  } else {
    float* Cf = (float*)Cout;
#pragma unroll
    for (int j = 0; j < 4; ++j) {
      const int gn = n0 + wn + j * 16 + l15;
      const float bj = bias[gn];
#pragma unroll
      for (int i = 0; i < 4; ++i) {
        const int gm = m0 + wm + i * 16 + l4 * 4;
#pragma unroll
        for (int r = 0; r < 4; ++r) {
          float v = acc[i][j][r] + bj;
          if (EPI == 2) v += R[(size_t)(gm + r) * N + gn];
          Cf[(size_t)(gm + r) * N + gn] = v;
        }
      }
    }
  }
}

// ---------------- MFMA flash attention, swapped 32x32x16 structure ----------
__global__ __launch_bounds__(256, 2) void attn_kernel(
    const bf16_t* __restrict__ qkv, const bf16_t* __restrict__ Vt,
    const float* __restrict__ mask, bf16_t* __restrict__ ctx) {
  __shared__ __align__(16) bf16_t K_lds[64 * 72];   // [kv][d]
  __shared__ __align__(16) bf16_t Vt_lds[64 * 72];  // [dv][kv]
  const int tid = threadIdx.x;
  const int lane = tid & 63;
  const int w = tid >> 6;
  const int l31 = lane & 31;
  const int h = lane >> 5;
  const int q0 = blockIdx.x * 128;
  const int head = blockIdx.y;
  const int b = blockIdx.z;
  const int qrow = q0 + w * 32 + l31;

  bf16x8 qf[4];
  {
    const bf16_t* qp = qkv + (size_t)(b * SS + qrow) * 3072 + head * 64 + 8 * h;
#pragma unroll
    for (int ks = 0; ks < 4; ++ks) qf[ks] = *(const bf16x8*)(qp + 16 * ks);
  }

  const int srow = tid >> 2;
  const int scol = (tid & 3) * 16;

  float m = -3.0e38f, l = 0.0f;
  f32x16 cacc0 = {};
  f32x16 cacc1 = {};

  for (int kv0 = 0; kv0 < SS; kv0 += 64) {
    const bf16_t* kp =
        qkv + (size_t)(b * SS + kv0 + srow) * 3072 + 1024 + head * 64 + scol;
    const bf16_t* vp =
        Vt + ((size_t)(b * NH + head) * 64 + srow) * SS + kv0 + scol;
    const bf16x8 k0 = *(const bf16x8*)kp;
    const bf16x8 k1 = *(const bf16x8*)(kp + 8);
    const bf16x8 v0 = *(const bf16x8*)vp;
    const bf16x8 v1 = *(const bf16x8*)(vp + 8);
    float4 mv[8];
#pragma unroll
    for (int k2 = 0; k2 < 8; ++k2)
      mv[k2] = *(const float4*)(mask + (size_t)b * SS + kv0 + 8 * k2 + 4 * h);
    __syncthreads();
    *(bf16x8*)(K_lds + srow * 72 + scol) = k0;
    *(bf16x8*)(K_lds + srow * 72 + scol + 8) = k1;
    *(bf16x8*)(Vt_lds + srow * 72 + scol) = v0;
    *(bf16x8*)(Vt_lds + srow * 72 + scol + 8) = v1;
    __syncthreads();

    f32x16 sacc0 = {};
    f32x16 sacc1 = {};
#pragma unroll
    for (int ks = 0; ks < 4; ++ks) {
      const bf16x8 kf0 = *(const bf16x8*)(K_lds + l31 * 72 + 16 * ks + 8 * h);
      const bf16x8 kf1 =
          *(const bf16x8*)(K_lds + (l31 + 32) * 72 + 16 * ks + 8 * h);
      sacc0 = __builtin_amdgcn_mfma_f32_32x32x16_bf16(kf0, qf[ks], sacc0, 0, 0, 0);
      sacc1 = __builtin_amdgcn_mfma_f32_32x32x16_bf16(kf1, qf[ks], sacc1, 0, 0, 0);
    }

    float ps[32];
    float tmax = -3.0e38f;
#pragma unroll
    for (int r = 0; r < 16; ++r) {
      const float s0 = sacc0[r] * 0.125f + mv[(r >> 2)][r & 3];
      const float s1 = sacc1[r] * 0.125f + mv[(r >> 2) + 4][r & 3];
      ps[r] = s0;
      ps[16 + r] = s1;
      tmax = fmaxf(tmax, fmaxf(s0, s1));
    }
    tmax = fmaxf(tmax, __shfl_xor(tmax, 32, 64));
    if (__any(tmax > m + 8.0f)) {
      const float mnew = fmaxf(m, tmax);
      const float sc = __expf(m - mnew);
      m = mnew;
      l *= sc;
#pragma unroll
      for (int r = 0; r < 16; ++r) {
        const float scr = __shfl(sc, (r & 3) + 8 * (r >> 2) + 4 * h, 64);
        cacc0[r] *= scr;
        cacc1[r] *= scr;
      }
    }
    float ls = 0.0f;
#pragma unroll
    for (int i = 0; i < 32; ++i) {
      ps[i] = __expf(ps[i] - m);
      ls += ps[i];
    }
    l += ls + __shfl_xor(ls, 32, 64);

    unsigned pw0[8], pw1[8];
#pragma unroll
    for (int k = 0; k < 8; ++k) {
      const int base = (k >> 2) * 16 + (k & 3) * 4;
      pw0[k] = pack2_bf16(ps[base + 0], ps[base + 1]);
      pw1[k] = pack2_bf16(ps[base + 2], ps[base + 3]);
    }
#pragma unroll
    for (int t = 0; t < 4; ++t) {
      const unsigned e0 = h ? pw0[2 * t] : pw0[2 * t + 1];
      const unsigned e1 = h ? pw1[2 * t] : pw1[2 * t + 1];
      const unsigned o0 = (unsigned)__shfl_xor((int)e0, 32, 64);
      const unsigned o1 = (unsigned)__shfl_xor((int)e1, 32, 64);
      const unsigned a0 = h ? pw0[2 * t + 1] : pw0[2 * t];
      const unsigned a1 = h ? pw1[2 * t + 1] : pw1[2 * t];
      union { unsigned u[4]; bf16x8 v; } pu;
      pu.u[0] = h ? o0 : a0;
      pu.u[1] = h ? o1 : a1;
      pu.u[2] = h ? a0 : o0;
      pu.u[3] = h ? a1 : o1;
      const bf16x8 vf0 = *(const bf16x8*)(Vt_lds + l31 * 72 + 16 * t + 8 * h);
      const bf16x8 vf1 =
          *(const bf16x8*)(Vt_lds + (l31 + 32) * 72 + 16 * t + 8 * h);
      cacc0 = __builtin_amdgcn_mfma_f32_32x32x16_bf16(pu.v, vf0, cacc0, 0, 0, 0);
      cacc1 = __builtin_amdgcn_mfma_f32_32x32x16_bf16(pu.v, vf1, cacc1, 0, 0, 0);
    }
  }

  const float linv = 1.0f / l;
#pragma unroll
  for (int r = 0; r < 16; ++r) {
    const int rq = (r & 3) + 8 * (r >> 2) + 4 * h;
    const float li = __shfl(linv, rq, 64);
    const int grow = q0 + w * 32 + rq;
    bf16_t* op = ctx + (size_t)(b * SS + grow) * 1024 + head * 64 + l31;
    op[0] = (bf16_t)(cacc0[r] * li);
    op[32] = (bf16_t)(cacc1[r] * li);
  }
}

extern "C" void kernel_launch(void* const* d_in, const int* in_sizes, int n_in,
                              void* d_out, int out_size, void* d_ws, size_t ws_size,
                              hipStream_t stream) {
  const float* input    = (const float*)d_in[0];
  const float* mask     = (const float*)d_in[1];
  const float* norm_w   = (const float*)d_in[2];
  const float* norm_b   = (const float*)d_in[3];
  const float* qkv_w    = (const float*)d_in[4];
  const float* qkv_b    = (const float*)d_in[5];
  const float* attn_ow  = (const float*)d_in[6];
  const float* attn_ob  = (const float*)d_in[7];
  const float* attn_nw  = (const float*)d_in[8];
  const float* attn_nb  = (const float*)d_in[9];
  const float* inter_w  = (const float*)d_in[10];
  const float* inter_b  = (const float*)d_in[11];
  const float* output_w = (const float*)d_in[12];
  const float* output_b = (const float*)d_in[13];

  char* ws = (char*)d_ws;
  const size_t off_xln = 0;
  const size_t off_qkv = 16777216;
  const size_t off_vt  = 67108864;
  const size_t off_ctx = 83886080;
  const size_t off_ao  = 100663296;
  const size_t off_wq  = 134217728;
  const size_t off_wo  = 140509184;
  const size_t off_wi  = 142606336;
  const size_t off_w2  = 150994944;
  const size_t NEED    = 159383552;
  if (ws_size < NEED) return;

  bf16_t* x_ln  = (bf16_t*)(ws + off_xln);
  bf16_t* qkvb  = (bf16_t*)(ws + off_qkv);
  bf16_t* VtB   = (bf16_t*)(ws + off_vt);
  bf16_t* ctxb  = (bf16_t*)(ws + off_ctx);
  bf16_t* y_ln  = (bf16_t*)(ws + off_ctx);
  float*  a_out = (float*)(ws + off_ao);
  bf16_t* wq_t  = (bf16_t*)(ws + off_wq);
  bf16_t* wo_t  = (bf16_t*)(ws + off_wo);
  bf16_t* wi_t  = (bf16_t*)(ws + off_wi);
  bf16_t* w2_t  = (bf16_t*)(ws + off_w2);
  bf16_t* act   = (bf16_t*)(ws + off_xln);

  const int M = BB * SS;  // 8192

  wt_kernel<<<dim3(3072 / 32, 1024 / 32), 256, 0, stream>>>(qkv_w, wq_t, 1024, 3072);
  wt_kernel<<<dim3(1024 / 32, 1024 / 32), 256, 0, stream>>>(attn_ow, wo_t, 1024, 1024);
  wt_kernel<<<dim3(4096 / 32, 1024 / 32), 256, 0, stream>>>(inter_w, wi_t, 1024, 4096);
  wt_kernel<<<dim3(1024 / 32, 4096 / 32), 256, 0, stream>>>(output_w, w2_t, 4096, 1024);

  ln_kernel<<<M, 256, 0, stream>>>(input, norm_w, norm_b, x_ln);
  gemm_bf16<0, true><<<dim3(3072 / 128, M / 128), 256, 0, stream>>>(
      x_ln, wq_t, qkv_b, nullptr, qkvb, M, 3072, 1024);
  vtrans_kernel<<<dim3(SS / 256, NH, BB), 256, 0, stream>>>(qkvb, VtB);
  attn_kernel<<<dim3(SS / 128, NH, BB), 256, 0, stream>>>(qkvb, VtB, mask, ctxb);
  gemm_bf16<2, false><<<dim3(1024 / 128, M / 128), 256, 0, stream>>>(
      ctxb, wo_t, attn_ob, input, a_out, M, 1024, 1024);
  ln_kernel<<<M, 256, 0, stream>>>(a_out, attn_nw, attn_nb, y_ln);
  gemm_bf16<1, true><<<dim3(4096 / 128, M / 128), 256, 0, stream>>>(
      y_ln, wi_t, inter_b, nullptr, act, M, 4096, 1024);
  gemm_bf16<2, false><<<dim3(1024 / 128, M / 128), 256, 0, stream>>>(
      act, w2_t, output_b, a_out, (float*)d_out, M, 1024, 4096);
}